// Round 18
// baseline (47.589 us; speedup 1.0000x reference)
//
#include <hip/hip_runtime.h>

#define NB   64
#define LSEQ 8192
#define NW   8190
#define HD   90
#define AMPF 28.5f

typedef _Float16 half8  __attribute__((ext_vector_type(8)));
typedef float    f32x4  __attribute__((ext_vector_type(4)));
typedef __fp16   fp16x2 __attribute__((ext_vector_type(2)));

union FragU { uint4 u; half8 h; };

__device__ __forceinline__ unsigned pk2(float a, float b) {
  fp16x2 v = __builtin_amdgcn_cvt_pkrtz(a, b);
  return __builtin_bit_cast(unsigned, v);
}
__device__ __forceinline__ unsigned pkmax0(unsigned w) {
  unsigned r;
  asm("v_pk_max_f16 %0, %1, %2" : "=v"(r) : "v"(w), "v"(0u));
  return r;
}
__device__ __forceinline__ int imin(int a, int b) { return a < b ? a : b; }

// ============================================================================
// 16x16x32 swapped formulation: D[n][w] = sum_k W[k][n] * H[k][w].
// A-operand = weights (row n = 16*t2 + (lane&15)), B-operand = activations
// (col w = lane&15). CUSTOM K-SLOT MAP, identical on A and B (HW maps slots
// symmetrically; any agreed bijection cancels):
//     slot (g = lane>>4, i=0..7) of k-step s:  k = 32s + 16*(i>>2) + 4g + (i&3)
// Chosen so that next-layer B-frags are EXACTLY the pk2-packed C values each
// lane already holds (C: col=lane&15, row n = 16*t2 + 4g + r) -> transition is
// 12 pk2 + 12 pk_max per 16-window tile, zero cross-lane ops, zero LDS.
// Layer-1 uses natural g==0 slots k=i (kin=8: 7 inputs + bias-one).
// Bias-propagation: n==90 row outputs 1.0 through every layer (A[n=90][k=kin]=1).
// frag ids: 0..5 layer1 (t2=f) | 6..77 hidden (f=6+L*18+t2*3+s) | 78..80 layer6
// ============================================================================
__global__ void dnpu_pack(const float* __restrict__ W1, const float* __restrict__ b1,
                          const float* __restrict__ W2, const float* __restrict__ b2,
                          const float* __restrict__ W3, const float* __restrict__ b3,
                          const float* __restrict__ W4, const float* __restrict__ b4,
                          const float* __restrict__ W5, const float* __restrict__ b5,
                          const float* __restrict__ W6, const float* __restrict__ b6,
                          uint4* __restrict__ frags) {
  int tid = blockIdx.x * blockDim.x + threadIdx.x;
  if (tid >= 81 * 64) return;
  int f = tid >> 6, lane = tid & 63;
  int nl = lane & 15, g = lane >> 4;
  FragU u;
  if (f < 6) {
    int n = 16 * f + nl;
#pragma unroll
    for (int i = 0; i < 8; ++i) {
      float val = 0.f;
      if (g == 0) {                       // layer-1 slots: k = i (g==0 only)
        if (n < HD) { if (i < 7) val = W1[i * HD + n]; else val = b1[n]; }
        else if (n == HD && i == 7) val = 1.0f;          // bias-propagation
      }
      u.h[i] = (_Float16)val;
    }
  } else if (f < 78) {
    int q = f - 6, L = q / 18, r = q % 18, t2 = r / 3, s = r % 3;
    const float* W    = (L == 0) ? W2 : (L == 1) ? W3 : (L == 2) ? W4 : W5;
    const float* bias = (L == 0) ? b2 : (L == 1) ? b3 : (L == 2) ? b4 : b5;
    int n = 16 * t2 + nl;
#pragma unroll
    for (int i = 0; i < 8; ++i) {
      int k = 32 * s + ((i >> 2) << 4) + (g << 2) + (i & 3);   // custom map
      float val = 0.f;
      if (n < HD)      { if (k < HD) val = W[k * HD + n]; else if (k == HD) val = bias[n]; }
      else if (n == HD && k == HD) val = 1.0f;                 // bias-propagation
      u.h[i] = (_Float16)val;
    }
  } else {
    int s = f - 78;
    int n = nl;                                        // t2 = 0, only n==0 real
#pragma unroll
    for (int i = 0; i < 8; ++i) {
      int k = 32 * s + ((i >> 2) << 4) + (g << 2) + (i & 3);
      float val = 0.f;
      if (n == 0) { if (k < HD) val = W6[k]; else if (k == HD) val = b6[0]; }
      u.h[i] = (_Float16)val;
    }
  }
  frags[f * 64 + lane] = u.u;
}

// one hidden 96x96 layer over 2 tiles; weight frags from LDS, streamed 3 at a
// time; transition = pack only (custom slot map), in-register.
__device__ __forceinline__ void hidden(const uint4* __restrict__ wfr, int lane,
                                       uint4 (&B)[2][3], const f32x4& zz) {
  unsigned P[2][6][2];
#pragma unroll
  for (int t2 = 0; t2 < 6; ++t2) {
    FragU Wf[3];
#pragma unroll
    for (int s = 0; s < 3; ++s) Wf[s].u = wfr[(t2 * 3 + s) * 64 + lane];
#pragma unroll
    for (int t = 0; t < 2; ++t) {
      f32x4 a = __builtin_amdgcn_mfma_f32_16x16x32_f16(
                  Wf[0].h, __builtin_bit_cast(half8, B[t][0]), zz, 0, 0, 0);
      a = __builtin_amdgcn_mfma_f32_16x16x32_f16(
                  Wf[1].h, __builtin_bit_cast(half8, B[t][1]), a, 0, 0, 0);
      a = __builtin_amdgcn_mfma_f32_16x16x32_f16(
                  Wf[2].h, __builtin_bit_cast(half8, B[t][2]), a, 0, 0, 0);
      P[t][t2][0] = pkmax0(pk2(a[0], a[1]));
      P[t][t2][1] = pkmax0(pk2(a[2], a[3]));
    }
  }
#pragma unroll
  for (int t = 0; t < 2; ++t)
#pragma unroll
    for (int s = 0; s < 3; ++s)
      B[t][s] = make_uint4(P[t][2 * s][0], P[t][2 * s][1],
                           P[t][2 * s + 1][0], P[t][2 * s + 1][1]);
}

// ---------------- main kernel ----------------
// 16x16 shape -> f32x4 accumulators: tiny unified VGPR+AGPR footprint (the
// 32x32 f32x16 accs were the hidden residency cap, R4-R15: pinned 2 waves/SIMD).
// LDS = 18 KB (one layer's frags), restaged per layer.
__global__ __launch_bounds__(256, 2)
void dnpu_mfma(const float* __restrict__ x, const float* __restrict__ cv,
               const uint4* __restrict__ frags, float* __restrict__ out) {
  __shared__ uint4 wfr[18 * 64];             // 18,432 B
  const int tid  = threadIdx.x;
  const int lane = tid & 63, wid = tid >> 6;
  const int g = lane >> 4, nl = lane & 15;
  const int b = blockIdx.y;

  f32x4 zz = (f32x4)(0.f);
  asm volatile("" : "+v"(zz));               // opaque zero C-operand

  // stage layer-2 frags
  for (int i = tid; i < 18 * 64; i += 256) wfr[i] = frags[6 * 64 + i];

  const float c0 = cv[0], c1 = cv[1], c2 = cv[2], c3 = cv[3];
  const float* xr = x + (size_t)b * LSEQ;
  const int rowbase = blockIdx.x * 128 + wid * 32;   // 2 tiles x 16 windows

  uint4 B[2][3];

  // ---- layer 1 -> B ----
  {
    FragU A1[6];
#pragma unroll
    for (int t2 = 0; t2 < 6; ++t2) A1[t2].u = frags[t2 * 64 + lane];
    unsigned P[2][6][2];
#pragma unroll
    for (int t = 0; t < 2; ++t) {
      const int w  = rowbase + t * 16 + nl;
      const int xi = imin(w, LSEQ - 3);
      const float x0 = xr[xi], x1 = xr[xi + 1], x2 = xr[xi + 2];
      half8 B1;
#pragma unroll
      for (int i = 0; i < 8; ++i) B1[i] = (_Float16)0.f;
      if (g == 0) {
        B1[0] = (_Float16)c0; B1[1] = (_Float16)c1;
        B1[2] = (_Float16)x0; B1[3] = (_Float16)x1; B1[4] = (_Float16)x2;
        B1[5] = (_Float16)c2; B1[6] = (_Float16)c3; B1[7] = (_Float16)1.0f;
      }
#pragma unroll
      for (int t2 = 0; t2 < 6; ++t2) {
        f32x4 a = __builtin_amdgcn_mfma_f32_16x16x32_f16(A1[t2].h, B1, zz, 0, 0, 0);
        P[t][t2][0] = pkmax0(pk2(a[0], a[1]));
        P[t][t2][1] = pkmax0(pk2(a[2], a[3]));
      }
    }
#pragma unroll
    for (int t = 0; t < 2; ++t)
#pragma unroll
      for (int s = 0; s < 3; ++s)
        B[t][s] = make_uint4(P[t][2 * s][0], P[t][2 * s][1],
                             P[t][2 * s + 1][0], P[t][2 * s + 1][1]);
  }

  __syncthreads();                                        // L2 frags ready
  hidden(wfr, lane, B, zz);                               // L2
  __syncthreads();
  for (int i = tid; i < 18 * 64; i += 256) wfr[i] = frags[(6 + 18) * 64 + i];
  __syncthreads();
  hidden(wfr, lane, B, zz);                               // L3
  __syncthreads();
  for (int i = tid; i < 18 * 64; i += 256) wfr[i] = frags[(6 + 36) * 64 + i];
  __syncthreads();
  hidden(wfr, lane, B, zz);                               // L4
  __syncthreads();
  for (int i = tid; i < 18 * 64; i += 256) wfr[i] = frags[(6 + 54) * 64 + i];
  __syncthreads();
  hidden(wfr, lane, B, zz);                               // L5

  // ---- layer 6: 96 -> 1 (n==0 lanes: g==0, acc elem 0), then * AMP ----
  {
    FragU A6[3];
#pragma unroll
    for (int s = 0; s < 3; ++s) A6[s].u = frags[(78 + s) * 64 + lane];
#pragma unroll
    for (int t = 0; t < 2; ++t) {
      f32x4 a = __builtin_amdgcn_mfma_f32_16x16x32_f16(
                  A6[0].h, __builtin_bit_cast(half8, B[t][0]), zz, 0, 0, 0);
      a = __builtin_amdgcn_mfma_f32_16x16x32_f16(
                  A6[1].h, __builtin_bit_cast(half8, B[t][1]), a, 0, 0, 0);
      a = __builtin_amdgcn_mfma_f32_16x16x32_f16(
                  A6[2].h, __builtin_bit_cast(half8, B[t][2]), a, 0, 0, 0);
      if (g == 0) {
        const int row = rowbase + t * 16 + nl;
        if (row < NW) out[(size_t)b * NW + row] = a[0] * AMPF;
      }
    }
  }
}

extern "C" void kernel_launch(void* const* d_in, const int* in_sizes, int n_in,
                              void* d_out, int out_size, void* d_ws, size_t ws_size,
                              hipStream_t stream) {
  const float* x  = (const float*)d_in[0];
  const float* cv = (const float*)d_in[1];
  const float* W1 = (const float*)d_in[2];
  const float* b1 = (const float*)d_in[3];
  const float* W2 = (const float*)d_in[4];
  const float* b2 = (const float*)d_in[5];
  const float* W3 = (const float*)d_in[6];
  const float* b3 = (const float*)d_in[7];
  const float* W4 = (const float*)d_in[8];
  const float* b4 = (const float*)d_in[9];
  const float* W5 = (const float*)d_in[10];
  const float* b5 = (const float*)d_in[11];
  const float* W6 = (const float*)d_in[12];
  const float* b6 = (const float*)d_in[13];
  float* out = (float*)d_out;
  uint4* frags = (uint4*)d_ws;   // 81 * 64 * 16 B = 82,944 B

  hipLaunchKernelGGL(dnpu_pack, dim3(21), dim3(256), 0, stream,
                     W1, b1, W2, b2, W3, b3, W4, b4, W5, b5, W6, b6, frags);
  // 8192 windows: 64 blocks x (4 waves * 32 windows)
  hipLaunchKernelGGL(dnpu_mfma, dim3(64, NB), dim3(256), 0, stream,
                     x, cv, frags, out);
}